// Round 2
// baseline (10569.479 us; speedup 1.0000x reference)
//
#include <hip/hip_runtime.h>

// MultiHeadSelfAttention (faithful: single logical head over full D=1024).
// B=2, S=4096, D=1024, SCALE = 8.0 (MULTIPLY by sqrt(head_dim)).
//
// Round 2: all-fp32 correctness baseline. I/O dtypes are FP32 (proven by npz
// byte sizes: 46.7MB in / 31MB out can only be fp32). Round 1's NaN was fp32
// bits misread as bf16.
// ws layout: Q | K | V | AO, each B*S*D fp32 = 32 MiB -> 128 MiB total.

#define DIM    1024
#define SEQ    4096
#define NBATCH 2

// C[M,1024] = A[M,1024] @ W[1024,1024]   (W row-major [in,out], y = x @ W)
// BM=BN=128, BK=32, 256 threads, 8x8 per-thread tile. All fp32.
__global__ __launch_bounds__(256) void gemm_nk(const float* __restrict__ A,
                                               const float* __restrict__ W,
                                               float* __restrict__ C)
{
    constexpr int BK = 32;
    constexpr int LDA = 132, LDB = 132;   // 128+4 pad
    __shared__ float As[BK * LDA];        // [k][m] (transposed on store)
    __shared__ float Bs[BK * LDB];        // [k][n]
    const int t  = threadIdx.x;
    const int bn = blockIdx.x * 128;
    const int bm = blockIdx.y * 128;

    float acc[8][8];
    #pragma unroll
    for (int i = 0; i < 8; ++i)
        #pragma unroll
        for (int j = 0; j < 8; ++j) acc[i][j] = 0.f;

    const int tr = (t >> 4) * 8;   // row offset of this thread's 8x8 tile
    const int tc = (t & 15) * 8;   // col offset
    const int ar = t >> 1;         // A staging: row in tile (0..127)
    const int ac = (t & 1) * 16;   // A staging: first col (0 or 16)
    const int wr = t >> 3;         // W staging: row (0..31)
    const int wc = (t & 7) * 16;   // W staging: first col

    for (int k0 = 0; k0 < DIM; k0 += BK) {
        // stage A tile (128 x 32) -> As[k][m]
        const float* pa = A + (size_t)(bm + ar) * DIM + (k0 + ac);
        #pragma unroll
        for (int q = 0; q < 4; ++q) {
            float4 f = *(const float4*)(pa + q * 4);
            As[(ac + q*4 + 0) * LDA + ar] = f.x;
            As[(ac + q*4 + 1) * LDA + ar] = f.y;
            As[(ac + q*4 + 2) * LDA + ar] = f.z;
            As[(ac + q*4 + 3) * LDA + ar] = f.w;
        }
        // stage W tile (32 x 128) -> Bs[k][n]
        const float* pw = W + (size_t)(k0 + wr) * DIM + (bn + wc);
        #pragma unroll
        for (int q = 0; q < 4; ++q)
            *(float4*)&Bs[wr * LDB + wc + q*4] = *(const float4*)(pw + q * 4);
        __syncthreads();
        #pragma unroll 8
        for (int k = 0; k < BK; ++k) {
            float a[8], b[8];
            *(float4*)(a)     = *(const float4*)&As[k * LDA + tr];
            *(float4*)(a + 4) = *(const float4*)&As[k * LDA + tr + 4];
            *(float4*)(b)     = *(const float4*)&Bs[k * LDB + tc];
            *(float4*)(b + 4) = *(const float4*)&Bs[k * LDB + tc + 4];
            #pragma unroll
            for (int i = 0; i < 8; ++i)
                #pragma unroll
                for (int j = 0; j < 8; ++j)
                    acc[i][j] = fmaf(a[i], b[j], acc[i][j]);
        }
        __syncthreads();
    }

    #pragma unroll
    for (int i = 0; i < 8; ++i) {
        float* cp = C + (size_t)(bm + tr + i) * DIM + (bn + tc);
        *(float4*)(cp)     = make_float4(acc[i][0], acc[i][1], acc[i][2], acc[i][3]);
        *(float4*)(cp + 4) = make_float4(acc[i][4], acc[i][5], acc[i][6], acc[i][7]);
    }
}

// Fused flash-style attention, fp32. Grid: (SEQ/16, NBATCH), 256 threads.
// Per block: 16 q-rows. Q staged in LDS, K/V tiles (16 rows) share one buffer.
// Online softmax; O accumulator in registers (64 f32/thread).
__global__ __launch_bounds__(256) void attn_fused(const float* __restrict__ Q,
                                                  const float* __restrict__ K,
                                                  const float* __restrict__ V,
                                                  float* __restrict__ AO)
{
    constexpr int BQ = 16, TK = 16, LQ = DIM + 4;
    __shared__ float q_s[BQ * LQ];
    __shared__ float kv_s[TK * LQ];
    __shared__ float s_raw[BQ * 17];
    const int t = threadIdx.x;
    const size_t base = (size_t)blockIdx.y * SEQ * DIM;
    const int q0 = blockIdx.x * BQ;

    // load Q block (16 x 1024 f32)
    for (int x = t; x < BQ * (DIM / 4); x += 256) {
        int r = x >> 8, c = (x & 255) * 4;
        *(float4*)&q_s[r * LQ + c] = *(const float4*)&Q[base + (size_t)(q0 + r) * DIM + c];
    }

    const int si = t & 15;   // my q-row
    const int sj = t >> 4;   // my k-col in S-step; also my dim-group for O
    float o_acc[64];
    #pragma unroll
    for (int d = 0; d < 64; ++d) o_acc[d] = 0.f;
    float m_run = -INFINITY, l_run = 0.f;

    for (int kt = 0; kt < SEQ; kt += TK) {
        __syncthreads();   // prev iter done reading kv_s / s_raw
        for (int x = t; x < TK * (DIM / 4); x += 256) {           // K tile
            int r = x >> 8, c = (x & 255) * 4;
            *(float4*)&kv_s[r * LQ + c] = *(const float4*)&K[base + (size_t)(kt + r) * DIM + c];
        }
        __syncthreads();
        // S = (Q K^T) * 8 ; one dot per thread; 4 independent FMA chains
        {
            const float* qp = &q_s[si * LQ];
            const float* kp = &kv_s[sj * LQ];
            float s0 = 0.f, s1 = 0.f, s2 = 0.f, s3 = 0.f;
            #pragma unroll 8
            for (int d = 0; d < DIM; d += 4) {
                float4 qa = *(const float4*)(qp + d);
                float4 ka = *(const float4*)(kp + d);
                s0 = fmaf(qa.x, ka.x, s0); s1 = fmaf(qa.y, ka.y, s1);
                s2 = fmaf(qa.z, ka.z, s2); s3 = fmaf(qa.w, ka.w, s3);
            }
            s_raw[si * 17 + sj] = ((s0 + s1) + (s2 + s3)) * 8.0f;
        }
        __syncthreads();
        // online softmax update (replicated identically across row si's 16 threads)
        float m_tile = -INFINITY;
        #pragma unroll
        for (int j = 0; j < TK; ++j) m_tile = fmaxf(m_tile, s_raw[si * 17 + j]);
        float m_new = fmaxf(m_run, m_tile);
        float corr = __expf(m_run - m_new);
        float sum = 0.f;
        #pragma unroll
        for (int j = 0; j < TK; ++j) sum += __expf(s_raw[si * 17 + j] - m_new);
        l_run = l_run * corr + sum;
        m_run = m_new;
        #pragma unroll
        for (int d = 0; d < 64; ++d) o_acc[d] *= corr;
        // V tile into same buffer (S-step reads of K done at barrier above)
        for (int x = t; x < TK * (DIM / 4); x += 256) {
            int r = x >> 8, c = (x & 255) * 4;
            *(float4*)&kv_s[r * LQ + c] = *(const float4*)&V[base + (size_t)(kt + r) * DIM + c];
        }
        __syncthreads();
        // PV: O[si][sj*4 + 64c] += p_j * V[j][...]
        #pragma unroll 1
        for (int j = 0; j < TK; ++j) {
            float pj = __expf(s_raw[si * 17 + j] - m_run);
            const float* vp = &kv_s[j * LQ + sj * 4];
            #pragma unroll
            for (int c = 0; c < 16; ++c) {
                float4 v = *(const float4*)(vp + c * 64);
                o_acc[c*4 + 0] = fmaf(pj, v.x, o_acc[c*4 + 0]);
                o_acc[c*4 + 1] = fmaf(pj, v.y, o_acc[c*4 + 1]);
                o_acc[c*4 + 2] = fmaf(pj, v.z, o_acc[c*4 + 2]);
                o_acc[c*4 + 3] = fmaf(pj, v.w, o_acc[c*4 + 3]);
            }
        }
    }
    const float inv_l = 1.0f / l_run;
    for (int c = 0; c < 16; ++c) {
        float4 o = make_float4(o_acc[c*4+0] * inv_l, o_acc[c*4+1] * inv_l,
                               o_acc[c*4+2] * inv_l, o_acc[c*4+3] * inv_l);
        *(float4*)&AO[base + (size_t)(q0 + si) * DIM + sj * 4 + c * 64] = o;
    }
}

extern "C" void kernel_launch(void* const* d_in, const int* in_sizes, int n_in,
                              void* d_out, int out_size, void* d_ws, size_t ws_size,
                              hipStream_t stream) {
    const float* x  = (const float*)d_in[0];
    const float* Wq = (const float*)d_in[1];
    const float* Wk = (const float*)d_in[2];
    const float* Wv = (const float*)d_in[3];
    const float* Wo = (const float*)d_in[4];
    float* out = (float*)d_out;

    const size_t NB = (size_t)NBATCH * SEQ * DIM;   // 8,388,608
    float* ws = (float*)d_ws;
    float* Qf = ws;
    float* Kf = ws + NB;
    float* Vf = ws + 2 * NB;
    float* AO = ws + 3 * NB;                        // total 128 MiB fp32

    dim3 gg(DIM / 128, (NBATCH * SEQ) / 128);       // (8, 64)
    dim3 gb(256);
    hipLaunchKernelGGL(gemm_nk, gg, gb, 0, stream, x,  Wq, Qf);
    hipLaunchKernelGGL(gemm_nk, gg, gb, 0, stream, x,  Wk, Kf);
    hipLaunchKernelGGL(gemm_nk, gg, gb, 0, stream, x,  Wv, Vf);

    dim3 ga(SEQ / 16, NBATCH);                      // (256, 2)
    hipLaunchKernelGGL(attn_fused, ga, gb, 0, stream, Qf, Kf, Vf, AO);

    hipLaunchKernelGGL(gemm_nk, gg, gb, 0, stream, AO, Wo, out);
}

// Round 4
// 5419.535 us; speedup vs baseline: 1.9503x; 1.9503x over previous
//
#include <hip/hip_runtime.h>
#include <hip/hip_bf16.h>

// MultiHeadSelfAttention (faithful: single logical head over full D=1024).
// B=2, S=4096, D=1024, SCALE = 8.0.
//
// Round 4 = round 3 + missing include fixed (f2bf now pure bit-ops, RNE).
//  - projections: fp32 VALU GEMM with epilogues:
//      Q,K -> split bf16 (hi = bf16(acc), lo = bf16(acc-hi))  [3-pass QK^T]
//      V   -> bf16, written TRANSPOSED Vt[d][m] so PV B-frags are contiguous
//  - attn: 16 q-rows/block, 4 waves = 4 S-column groups of 16 (TK=64).
//      QK^T = Qh*Kh + Qh*Kl + Ql*Kh  (drops lo*lo; logit err ~1e-3)
//      online softmax fp32; P bf16; PV plain bf16 MFMA.
//  - ws: Qh|Ql|Kh|Kl|Vt (bf16, 16MB each) + AO (fp32, 32MB) = 112 MB.

#define DIM    1024
#define SEQ    4096
#define NBATCH 2

typedef unsigned short ushort_t;
typedef __attribute__((ext_vector_type(8))) short bf16x8;
typedef __attribute__((ext_vector_type(4))) float f32x4;

__device__ __forceinline__ float bf2f(ushort_t u) {
    union { unsigned int i; float f; } v; v.i = ((unsigned int)u) << 16; return v.f;
}
// round-to-nearest-even f32 -> bf16 (no NaN inputs in this problem)
__device__ __forceinline__ ushort_t f2bf(float f) {
    union { float f; unsigned int i; } v; v.f = f;
    unsigned int x = v.i + (0x7fffu + ((v.i >> 16) & 1u));
    return (ushort_t)(x >> 16);
}

// C[M,1024] = A[M,1024] @ W[1024,1024], fp32 compute.
// EPI 0: C fp32.  EPI 1: C1=hi bf16, C2=lo bf16.  EPI 2: C1 = bf16 transposed Vt[n][m], ld=8192.
template<int EPI>
__global__ __launch_bounds__(256) void gemm_nk(const float* __restrict__ A,
                                               const float* __restrict__ W,
                                               float* __restrict__ C,
                                               ushort_t* __restrict__ C1,
                                               ushort_t* __restrict__ C2)
{
    constexpr int BK = 32;
    constexpr int LDA = 132, LDB = 132;
    __shared__ float As[BK * LDA];
    __shared__ float Bs[BK * LDB];
    const int t  = threadIdx.x;
    const int bn = blockIdx.x * 128;
    const int bm = blockIdx.y * 128;

    float acc[8][8];
    #pragma unroll
    for (int i = 0; i < 8; ++i)
        #pragma unroll
        for (int j = 0; j < 8; ++j) acc[i][j] = 0.f;

    const int tr = (t >> 4) * 8;
    const int tc = (t & 15) * 8;
    const int ar = t >> 1;
    const int ac = (t & 1) * 16;
    const int wr = t >> 3;
    const int wc = (t & 7) * 16;

    for (int k0 = 0; k0 < DIM; k0 += BK) {
        const float* pa = A + (size_t)(bm + ar) * DIM + (k0 + ac);
        #pragma unroll
        for (int q = 0; q < 4; ++q) {
            float4 f = *(const float4*)(pa + q * 4);
            As[(ac + q*4 + 0) * LDA + ar] = f.x;
            As[(ac + q*4 + 1) * LDA + ar] = f.y;
            As[(ac + q*4 + 2) * LDA + ar] = f.z;
            As[(ac + q*4 + 3) * LDA + ar] = f.w;
        }
        const float* pw = W + (size_t)(k0 + wr) * DIM + (bn + wc);
        #pragma unroll
        for (int q = 0; q < 4; ++q)
            *(float4*)&Bs[wr * LDB + wc + q*4] = *(const float4*)(pw + q * 4);
        __syncthreads();
        #pragma unroll 8
        for (int k = 0; k < BK; ++k) {
            float a[8], b[8];
            *(float4*)(a)     = *(const float4*)&As[k * LDA + tr];
            *(float4*)(a + 4) = *(const float4*)&As[k * LDA + tr + 4];
            *(float4*)(b)     = *(const float4*)&Bs[k * LDB + tc];
            *(float4*)(b + 4) = *(const float4*)&Bs[k * LDB + tc + 4];
            #pragma unroll
            for (int i = 0; i < 8; ++i)
                #pragma unroll
                for (int j = 0; j < 8; ++j)
                    acc[i][j] = fmaf(a[i], b[j], acc[i][j]);
        }
        __syncthreads();
    }

    if constexpr (EPI == 0) {
        #pragma unroll
        for (int i = 0; i < 8; ++i) {
            float* cp = C + (size_t)(bm + tr + i) * DIM + (bn + tc);
            *(float4*)(cp)     = make_float4(acc[i][0], acc[i][1], acc[i][2], acc[i][3]);
            *(float4*)(cp + 4) = make_float4(acc[i][4], acc[i][5], acc[i][6], acc[i][7]);
        }
    } else if constexpr (EPI == 1) {
        #pragma unroll
        for (int i = 0; i < 8; ++i) {
            unsigned int uh[4], ul[4];
            #pragma unroll
            for (int p = 0; p < 4; ++p) {
                float a0 = acc[i][2*p], a1 = acc[i][2*p+1];
                ushort_t h0 = f2bf(a0), h1 = f2bf(a1);
                ushort_t l0 = f2bf(a0 - bf2f(h0)), l1 = f2bf(a1 - bf2f(h1));
                uh[p] = (unsigned int)h0 | ((unsigned int)h1 << 16);
                ul[p] = (unsigned int)l0 | ((unsigned int)l1 << 16);
            }
            size_t off = (size_t)(bm + tr + i) * DIM + (bn + tc);
            *(uint4*)&C1[off] = make_uint4(uh[0], uh[1], uh[2], uh[3]);
            *(uint4*)&C2[off] = make_uint4(ul[0], ul[1], ul[2], ul[3]);
        }
    } else {  // EPI == 2: transposed bf16: C1[(bn+tc+j)*8192 + bm+tr+i]
        #pragma unroll
        for (int j = 0; j < 8; ++j) {
            unsigned int u[4];
            #pragma unroll
            for (int p = 0; p < 4; ++p)
                u[p] = (unsigned int)f2bf(acc[2*p][j]) |
                       ((unsigned int)f2bf(acc[2*p+1][j]) << 16);
            *(uint4*)&C1[(size_t)(bn + tc + j) * (NBATCH*SEQ) + (bm + tr)] =
                make_uint4(u[0], u[1], u[2], u[3]);
        }
    }
}

// Fused flash attention with MFMA. Grid (SEQ/16, NBATCH), 256 threads (4 waves).
// Wave wv owns S-columns wv*16..+16 in the S-phase and d-range wv*256..+256 of O.
__global__ __launch_bounds__(256) void attn_mfma(const ushort_t* __restrict__ Qh,
                                                 const ushort_t* __restrict__ Ql,
                                                 const ushort_t* __restrict__ Kh,
                                                 const ushort_t* __restrict__ Kl,
                                                 const ushort_t* __restrict__ Vt,
                                                 float* __restrict__ AO)
{
    __shared__ ushort_t q_hi[16 * 1032];   // padded row stride 1032 (2064B)
    __shared__ ushort_t q_lo[16 * 1032];
    __shared__ ushort_t k_hi[64 * 136];    // d-chunk 128, stride 136 (272B)
    __shared__ ushort_t k_lo[64 * 136];
    __shared__ ushort_t v_s[256 * 72];     // [4 waves * 64 d][64 j], stride 72
    __shared__ float    s_raw[16 * 68];
    __shared__ float    red[512];          // pmax [0..255], psum [256..511]
    __shared__ ushort_t p_s[16 * 72];
    __shared__ float    m_s[16], l_s[16], corr_s[16];

    const int t    = threadIdx.x;
    const int lane = t & 63;
    const int wv   = t >> 6;
    const int lr   = lane & 15;   // frag row/col selector
    const int lg   = lane >> 4;   // k-group
    const int q0   = blockIdx.x * 16;
    const int b    = blockIdx.y;
    const size_t qbase = ((size_t)b * SEQ + q0) * DIM;
    const size_t kbase = (size_t)b * SEQ * DIM;

    // stage Q (16 x 1024, hi+lo)
    for (int i = t; i < 2048; i += 256) {
        int r = i >> 7, c8 = (i & 127) << 3;
        *(uint4*)&q_hi[r * 1032 + c8] = *(const uint4*)&Qh[qbase + (size_t)r * DIM + c8];
        *(uint4*)&q_lo[r * 1032 + c8] = *(const uint4*)&Ql[qbase + (size_t)r * DIM + c8];
    }
    if (t < 16) { m_s[t] = -INFINITY; l_s[t] = 0.f; }
    f32x4 o_acc[16];
    #pragma unroll
    for (int f = 0; f < 16; ++f) o_acc[f] = {0.f, 0.f, 0.f, 0.f};
    __syncthreads();

    for (int kt = 0; kt < SEQ; kt += 64) {
        // ---------- S phase: S[16 x 64] = (Q K^T) * 8, 3-pass split ----------
        f32x4 shh = {0.f,0.f,0.f,0.f}, shl = {0.f,0.f,0.f,0.f}, slh = {0.f,0.f,0.f,0.f};
        for (int d0 = 0; d0 < DIM; d0 += 128) {
            for (int i = t; i < 2048; i += 256) {
                int idx = i & 1023;
                int r = idx >> 4, c8 = (idx & 15) << 3;
                const ushort_t* src = (i < 1024 ? Kh : Kl) + kbase + (size_t)(kt + r) * DIM + d0 + c8;
                ushort_t*       dst = (i < 1024 ? k_hi : k_lo) + r * 136 + c8;
                *(uint4*)dst = *(const uint4*)src;
            }
            __syncthreads();
            #pragma unroll
            for (int ks = 0; ks < 4; ++ks) {
                const int qoff = lr * 1032 + d0 + ks * 32 + lg * 8;
                const int koff = (wv * 16 + lr) * 136 + ks * 32 + lg * 8;
                bf16x8 ah = *(const bf16x8*)&q_hi[qoff];
                bf16x8 al = *(const bf16x8*)&q_lo[qoff];
                bf16x8 bh = *(const bf16x8*)&k_hi[koff];
                bf16x8 bl = *(const bf16x8*)&k_lo[koff];
                shh = __builtin_amdgcn_mfma_f32_16x16x32_bf16(ah, bh, shh, 0, 0, 0);
                shl = __builtin_amdgcn_mfma_f32_16x16x32_bf16(ah, bl, shl, 0, 0, 0);
                slh = __builtin_amdgcn_mfma_f32_16x16x32_bf16(al, bh, slh, 0, 0, 0);
            }
            __syncthreads();
        }
        #pragma unroll
        for (int r = 0; r < 4; ++r)
            s_raw[(lg * 4 + r) * 68 + wv * 16 + lr] = (shh[r] + shl[r] + slh[r]) * 8.0f;
        __syncthreads();

        // ---------- online softmax ----------
        {   // (a) partial max
            int row = t & 15, c0 = (t >> 4) * 4;
            const float* sr = &s_raw[row * 68 + c0];
            red[row * 16 + (t >> 4)] = fmaxf(fmaxf(sr[0], sr[1]), fmaxf(sr[2], sr[3]));
        }
        __syncthreads();
        if (t < 16) {   // (b) row max, corr
            float mt = red[t * 16];
            #pragma unroll
            for (int j = 1; j < 16; ++j) mt = fmaxf(mt, red[t * 16 + j]);
            float mn = fmaxf(m_s[t], mt);
            corr_s[t] = __expf(m_s[t] - mn);
            m_s[t] = mn;
        }
        __syncthreads();
        {   // (c) p = exp(s - m), bf16; partial sums; rescale O
            int row = t & 15, c0 = (t >> 4) * 4;
            float mrow = m_s[row], ps = 0.f;
            #pragma unroll
            for (int j2 = 0; j2 < 4; ++j2) {
                float p = __expf(s_raw[row * 68 + c0 + j2] - mrow);
                ps += p;
                p_s[row * 72 + c0 + j2] = f2bf(p);
            }
            red[256 + row * 16 + (t >> 4)] = ps;
        }
        {
            float c4[4];
            #pragma unroll
            for (int r = 0; r < 4; ++r) c4[r] = corr_s[lg * 4 + r];
            #pragma unroll
            for (int f = 0; f < 16; ++f)
                #pragma unroll
                for (int r = 0; r < 4; ++r) o_acc[f][r] *= c4[r];
        }
        __syncthreads();
        if (t < 16) {   // (d) l update
            float s = red[256 + t * 16];
            #pragma unroll
            for (int j = 1; j < 16; ++j) s += red[256 + t * 16 + j];
            l_s[t] = l_s[t] * corr_s[t] + s;
        }

        // ---------- PV phase ----------
        bf16x8 pa0 = *(const bf16x8*)&p_s[lr * 72 + lg * 8];
        bf16x8 pa1 = *(const bf16x8*)&p_s[lr * 72 + 32 + lg * 8];
        for (int q = 0; q < 4; ++q) {
            for (int i = t; i < 2048; i += 256) {
                int j8 = (i & 7) << 3;
                int row = i >> 3;                    // w2*64 + dloc
                int w2 = row >> 6, dloc = row & 63;
                *(uint4*)&v_s[row * 72 + j8] =
                    *(const uint4*)&Vt[(size_t)(w2 * 256 + q * 64 + dloc) * (NBATCH*SEQ)
                                       + b * SEQ + kt + j8];
            }
            __syncthreads();
            #pragma unroll
            for (int fi = 0; fi < 4; ++fi) {
                const int vrow = (wv * 64 + fi * 16 + lr) * 72;
                bf16x8 vb0 = *(const bf16x8*)&v_s[vrow + lg * 8];
                bf16x8 vb1 = *(const bf16x8*)&v_s[vrow + 32 + lg * 8];
                o_acc[q*4+fi] = __builtin_amdgcn_mfma_f32_16x16x32_bf16(pa0, vb0, o_acc[q*4+fi], 0, 0, 0);
                o_acc[q*4+fi] = __builtin_amdgcn_mfma_f32_16x16x32_bf16(pa1, vb1, o_acc[q*4+fi], 0, 0, 0);
            }
            __syncthreads();
        }
    }

    __syncthreads();   // l_s from final (d)
    float inv[4];
    #pragma unroll
    for (int r = 0; r < 4; ++r) inv[r] = 1.0f / l_s[lg * 4 + r];
    #pragma unroll
    for (int f = 0; f < 16; ++f) {
        int d = wv * 256 + (f >> 2) * 64 + (f & 3) * 16 + lr;
        #pragma unroll
        for (int r = 0; r < 4; ++r)
            AO[qbase + (size_t)(lg * 4 + r) * DIM + d] = o_acc[f][r] * inv[r];
    }
}

extern "C" void kernel_launch(void* const* d_in, const int* in_sizes, int n_in,
                              void* d_out, int out_size, void* d_ws, size_t ws_size,
                              hipStream_t stream) {
    const float* x  = (const float*)d_in[0];
    const float* Wq = (const float*)d_in[1];
    const float* Wk = (const float*)d_in[2];
    const float* Wv = (const float*)d_in[3];
    const float* Wo = (const float*)d_in[4];
    float* out = (float*)d_out;

    const size_t NB = (size_t)NBATCH * SEQ * DIM;   // 8,388,608
    ushort_t* Qh = (ushort_t*)d_ws;
    ushort_t* Ql = Qh + NB;
    ushort_t* Kh = Ql + NB;
    ushort_t* Kl = Kh + NB;
    ushort_t* Vt = Kl + NB;                         // [1024][8192]
    float*    AO = (float*)(Vt + NB);               // fp32, 32MB. total 112MB

    dim3 gg(DIM / 128, (NBATCH * SEQ) / 128);       // (8, 64)
    dim3 gb(256);
    hipLaunchKernelGGL((gemm_nk<1>), gg, gb, 0, stream, x, Wq, nullptr, Qh, Ql);
    hipLaunchKernelGGL((gemm_nk<1>), gg, gb, 0, stream, x, Wk, nullptr, Kh, Kl);
    hipLaunchKernelGGL((gemm_nk<2>), gg, gb, 0, stream, x, Wv, nullptr, Vt, nullptr);

    dim3 ga(SEQ / 16, NBATCH);
    hipLaunchKernelGGL(attn_mfma, ga, gb, 0, stream, Qh, Ql, Kh, Kl, Vt, AO);

    hipLaunchKernelGGL((gemm_nk<0>), gg, gb, 0, stream, AO, Wo, out, nullptr, nullptr);
}

// Round 5
// 705.740 us; speedup vs baseline: 14.9764x; 7.6792x over previous
//
#include <hip/hip_runtime.h>

// MultiHeadSelfAttention (faithful: single logical head over full D=1024).
// B=2, S=4096, D=1024, SCALE = 8.0.
//
// Round 5: everything is an m97-style B^T GEMM (128^2 tile, global_load_lds,
// slot-swizzled LDS, 4 waves x 64x64 quadrant). S materialized per batch in
// half-column blocks (32MB) with 2-step online softmax merge; P written bf16
// in-place over S. Q/K projections & QK^T are 3-pass split-bf16 (fp32-grade
// logits); V/PV/Wo are 1-pass bf16.
//
// ws (MiB): xh 0..8 | xl 8..16 | WT[8] 16..32 | Qh 32..40 | Ql 40..48 (AO
// aliases Ql) | Kh 48..56 | Kl 56..64 | Vt 64..72 | S 72..104 | Oacc 104..120
// | stats 120..120.1

#define DIM    1024
#define SEQ    4096
#define NBATCH 2
#define MB     4096   // rows per batch

typedef unsigned short ushort_t;
typedef __attribute__((ext_vector_type(8))) short bf16x8;
typedef __attribute__((ext_vector_type(4))) float f32x4;

__device__ __forceinline__ float bf2f(ushort_t u) {
    union { unsigned int i; float f; } v; v.i = ((unsigned int)u) << 16; return v.f;
}
__device__ __forceinline__ ushort_t f2bf(float f) {   // RNE
    union { float f; unsigned int i; } v; v.f = f;
    unsigned int x = v.i + (0x7fffu + ((v.i >> 16) & 1u));
    return (ushort_t)(x >> 16);
}
__device__ __forceinline__ void load_lds16(const void* g, void* l) {
    __builtin_amdgcn_global_load_lds(
        (const __attribute__((address_space(1))) unsigned int*)g,
        (__attribute__((address_space(3))) unsigned int*)l, 16, 0, 0);
}

// ---------------- x -> hi/lo bf16 split (per batch slice) -----------------
__global__ __launch_bounds__(256) void split_x(const float* __restrict__ x,
                                               ushort_t* __restrict__ xh,
                                               ushort_t* __restrict__ xl)
{
    int i = (blockIdx.x * 256 + threadIdx.x) * 8;
    float4 f0 = *(const float4*)(x + i);
    float4 f1 = *(const float4*)(x + i + 4);
    float v[8] = {f0.x, f0.y, f0.z, f0.w, f1.x, f1.y, f1.z, f1.w};
    ushort_t h[8], l[8];
    #pragma unroll
    for (int k = 0; k < 8; ++k) {
        h[k] = f2bf(v[k]);
        l[k] = f2bf(v[k] - bf2f(h[k]));
    }
    unsigned int ph[4], pl[4];
    #pragma unroll
    for (int k = 0; k < 4; ++k) {
        ph[k] = (unsigned int)h[2*k] | ((unsigned int)h[2*k+1] << 16);
        pl[k] = (unsigned int)l[2*k] | ((unsigned int)l[2*k+1] << 16);
    }
    *(uint4*)(xh + i) = make_uint4(ph[0], ph[1], ph[2], ph[3]);
    *(uint4*)(xl + i) = make_uint4(pl[0], pl[1], pl[2], pl[3]);
}

// ---------------- W [1024][1024] f32 -> transposed hi/lo bf16 -------------
__global__ __launch_bounds__(256) void trans_split(const float* __restrict__ W,
                                                   ushort_t* __restrict__ Th,
                                                   ushort_t* __restrict__ Tl)
{
    __shared__ float tile[64][65];
    const int r0 = blockIdx.y * 64, c0 = blockIdx.x * 64;
    const int tr = threadIdx.x >> 4, tc = (threadIdx.x & 15) * 4;
    #pragma unroll
    for (int p = 0; p < 4; ++p) {
        int r = tr + p * 16;
        float4 f = *(const float4*)&W[(size_t)(r0 + r) * DIM + c0 + tc];
        tile[r][tc + 0] = f.x; tile[r][tc + 1] = f.y;
        tile[r][tc + 2] = f.z; tile[r][tc + 3] = f.w;
    }
    __syncthreads();
    #pragma unroll
    for (int p = 0; p < 4; ++p) {
        int i = tr + p * 16;                 // source col = out row (within tile)
        ushort_t h[4], l[4];
        #pragma unroll
        for (int k = 0; k < 4; ++k) {
            float v = tile[tc + k][i];
            h[k] = f2bf(v);
            l[k] = f2bf(v - bf2f(h[k]));
        }
        size_t off = (size_t)(c0 + i) * DIM + r0 + tc;
        *(ushort4*)&Th[off] = make_ushort4(h[0], h[1], h[2], h[3]);
        *(ushort4*)&Tl[off] = make_ushort4(l[0], l[1], l[2], l[3]);
    }
}

// ---------------- universal B^T MFMA GEMM ---------------------------------
// C[M,N] = scale * A[M,K] · B[N,K]^T ; bf16 operands (optionally hi+lo 3-pass
// accumulating into one f32 acc). 128x128 tile, 256 thr, 4 waves (64x64 each).
// LDS: per tile [128 rows][4 slots of 16B], slot swizzled: ps = s ^ ((r>>1)&3).
// EPI: 0 = f32 out (fout, scale)       1 = split hi/lo bf16 (o1,o2)
//      2 = bf16 transposed (o1[col*sC+row])
//      4 = (Oacc*corr[row] + acc) * invl[row] -> bf16 o1
template<int PASSES, int EPI>
__global__ __launch_bounds__(256, 2) void btgemm(
    const ushort_t* __restrict__ Ah, const ushort_t* __restrict__ Al,
    const ushort_t* __restrict__ Bh, const ushort_t* __restrict__ Bl,
    int sA, int sB, int Kdim,
    float* __restrict__ fout, ushort_t* __restrict__ o1, ushort_t* __restrict__ o2,
    const float* __restrict__ corr, const float* __restrict__ invl,
    const float* __restrict__ Oacc, int sC, float scale)
{
    __shared__ __align__(16) char smem[32768];   // Ah|Bh|Al|Bl tiles, 8KB each
    const int t    = threadIdx.x;
    const int lane = t & 63;
    const int wv   = t >> 6;
    const int lr   = lane & 15;
    const int lg   = lane >> 4;
    const int bn   = blockIdx.x * 128;
    const int bm   = blockIdx.y * 128;
    const int wr   = (wv >> 1) * 64;   // wave quadrant
    const int wc   = (wv & 1) * 64;

    f32x4 acc[4][4];
    #pragma unroll
    for (int i = 0; i < 4; ++i)
        #pragma unroll
        for (int j = 0; j < 4; ++j) acc[i][j] = {0.f, 0.f, 0.f, 0.f};

    const ushort_t* srcs[4] = {Ah, Bh, Al, Bl};
    constexpr int NCH = (PASSES == 3) ? 8 : 4;   // chunks per wave

    for (int k0 = 0; k0 < Kdim; k0 += 32) {
        // ---- stage tiles via global_load_lds (16B/lane, swizzled source) ----
        #pragma unroll
        for (int i = 0; i < NCH; ++i) {
            int cid  = i * 4 + wv;            // 0..4*NCH-1
            int tile = cid >> 3;              // 0:Ah 1:Bh 2:Al 3:Bl
            int ch   = cid & 7;               // rows ch*16..+16
            int unit = ch * 64 + lane;
            int row  = unit >> 2;
            int ls   = (unit & 3) ^ ((row >> 1) & 3);
            const ushort_t* g = srcs[tile]
                + (size_t)(((tile & 1) ? bn : bm) + row) * ((tile & 1) ? sB : sA)
                + k0 + ls * 8;
            load_lds16(g, smem + tile * 8192 + ch * 1024);
        }
        __syncthreads();
        // ---- fragments + MFMA ----
        bf16x8 ah[4], bh[4], al[4], bl[4];
        #pragma unroll
        for (int r = 0; r < 4; ++r) {
            int ra = wr + r * 16 + lr;
            int rb = wc + r * 16 + lr;
            ah[r] = *(const bf16x8*)(smem +         ((ra << 2) + (lg ^ ((ra >> 1) & 3))) * 16);
            bh[r] = *(const bf16x8*)(smem +  8192 + ((rb << 2) + (lg ^ ((rb >> 1) & 3))) * 16);
            if constexpr (PASSES == 3) {
                al[r] = *(const bf16x8*)(smem + 16384 + ((ra << 2) + (lg ^ ((ra >> 1) & 3))) * 16);
                bl[r] = *(const bf16x8*)(smem + 24576 + ((rb << 2) + (lg ^ ((rb >> 1) & 3))) * 16);
            }
        }
        #pragma unroll
        for (int i = 0; i < 4; ++i)
            #pragma unroll
            for (int j = 0; j < 4; ++j) {
                acc[i][j] = __builtin_amdgcn_mfma_f32_16x16x32_bf16(ah[i], bh[j], acc[i][j], 0, 0, 0);
                if constexpr (PASSES == 3) {
                    acc[i][j] = __builtin_amdgcn_mfma_f32_16x16x32_bf16(ah[i], bl[j], acc[i][j], 0, 0, 0);
                    acc[i][j] = __builtin_amdgcn_mfma_f32_16x16x32_bf16(al[i], bh[j], acc[i][j], 0, 0, 0);
                }
            }
        __syncthreads();
    }

    // ---- epilogue ----
    #pragma unroll
    for (int i = 0; i < 4; ++i)
        #pragma unroll
        for (int j = 0; j < 4; ++j) {
            int col = bn + wc + j * 16 + lr;
            #pragma unroll
            for (int reg = 0; reg < 4; ++reg) {
                int row = bm + wr + i * 16 + lg * 4 + reg;
                float v = acc[i][j][reg] * scale;
                if constexpr (EPI == 0) {
                    fout[(size_t)row * sC + col] = v;
                } else if constexpr (EPI == 1) {
                    ushort_t h = f2bf(v);
                    o1[(size_t)row * sC + col] = h;
                    o2[(size_t)row * sC + col] = f2bf(v - bf2f(h));
                } else if constexpr (EPI == 2) {
                    o1[(size_t)col * sC + row] = f2bf(v);
                } else {  // EPI == 4
                    float old = Oacc[(size_t)row * sC + col];
                    o1[(size_t)row * sC + col] = f2bf((old * corr[row] + v) * invl[row]);
                }
            }
        }
}

// ---------------- row softmax over a 2048-col half, in-place P ------------
// One wave per row; HALF=0 stores (m,l); HALF=1 merges and stores corr/invl.
template<int HALF>
__global__ __launch_bounds__(256) void softmax_half(float* __restrict__ S,
                                                    float* __restrict__ mrow,
                                                    float* __restrict__ lrow,
                                                    float* __restrict__ corr,
                                                    float* __restrict__ invl)
{
    const int row  = blockIdx.x * 4 + (threadIdx.x >> 6);
    const int lane = threadIdx.x & 63;
    float* sp = S + (size_t)row * 2048;

    float v[32];
    float m = -INFINITY;
    #pragma unroll
    for (int c = 0; c < 8; ++c) {
        float4 f = *(const float4*)(sp + (c * 64 + lane) * 4);
        v[c*4+0] = f.x; v[c*4+1] = f.y; v[c*4+2] = f.z; v[c*4+3] = f.w;
        m = fmaxf(m, fmaxf(fmaxf(f.x, f.y), fmaxf(f.z, f.w)));
    }
    #pragma unroll
    for (int off = 32; off; off >>= 1) m = fmaxf(m, __shfl_xor(m, off));

    float mN = m, c1 = 1.f;
    if constexpr (HALF == 1) {
        float m1 = mrow[row];
        mN = fmaxf(m, m1);
        c1 = __expf(m1 - mN);
    }
    float p[32], l = 0.f;
    #pragma unroll
    for (int k = 0; k < 32; ++k) { p[k] = __expf(v[k] - mN); l += p[k]; }
    #pragma unroll
    for (int off = 32; off; off >>= 1) l += __shfl_xor(l, off);

    if constexpr (HALF == 0) {
        if (lane == 0) { mrow[row] = mN; lrow[row] = l; }
    } else {
        if (lane == 0) {
            float L = lrow[row] * c1 + l;
            corr[row] = c1;
            invl[row] = 1.f / L;
        }
    }
    ushort_t* pp = (ushort_t*)sp;
    #pragma unroll
    for (int c = 0; c < 8; ++c) {
        ushort4 u = make_ushort4(f2bf(p[c*4+0]), f2bf(p[c*4+1]),
                                 f2bf(p[c*4+2]), f2bf(p[c*4+3]));
        *(ushort4*)(pp + (c * 64 + lane) * 4) = u;
    }
}

extern "C" void kernel_launch(void* const* d_in, const int* in_sizes, int n_in,
                              void* d_out, int out_size, void* d_ws, size_t ws_size,
                              hipStream_t stream) {
    const float* x  = (const float*)d_in[0];
    const float* Wq = (const float*)d_in[1];
    const float* Wk = (const float*)d_in[2];
    const float* Wv = (const float*)d_in[3];
    const float* Wo = (const float*)d_in[4];
    float* out = (float*)d_out;

    char* ws = (char*)d_ws;
    const size_t MiB = 1024 * 1024;
    ushort_t* xh  = (ushort_t*)(ws + 0 * MiB);
    ushort_t* xl  = (ushort_t*)(ws + 8 * MiB);
    ushort_t* WT  = (ushort_t*)(ws + 16 * MiB);       // 8 x 2MiB: qh,ql,kh,kl,vh,vl,oh,ol
    ushort_t* Qh  = (ushort_t*)(ws + 32 * MiB);
    ushort_t* Ql  = (ushort_t*)(ws + 40 * MiB);
    ushort_t* Kh  = (ushort_t*)(ws + 48 * MiB);
    ushort_t* Kl  = (ushort_t*)(ws + 56 * MiB);
    ushort_t* Vt  = (ushort_t*)(ws + 64 * MiB);       // [1024][4096]
    float*    S   = (float*)   (ws + 72 * MiB);       // [4096][2048] f32 / P bf16
    float*    Oac = (float*)   (ws + 104 * MiB);      // [4096][1024] f32
    ushort_t* AO  = Ql;                               // alias: Ql dead after S
    float*    mrow = (float*)(ws + 120 * MiB);
    float*    lrow = mrow + 4096;
    float*    corr = mrow + 8192;
    float*    invl = mrow + 12288;

    const size_t WSZ = (size_t)DIM * DIM;             // 1M elems per WT buf
    ushort_t* WqTh = WT;           ushort_t* WqTl = WT + WSZ;
    ushort_t* WkTh = WT + 2*WSZ;   ushort_t* WkTl = WT + 3*WSZ;
    ushort_t* WvTh = WT + 4*WSZ;   ushort_t* WvTl = WT + 5*WSZ;
    ushort_t* WoTh = WT + 6*WSZ;   ushort_t* WoTl = WT + 7*WSZ;

    dim3 blk(256);
    dim3 gT(16, 16);
    hipLaunchKernelGGL(trans_split, gT, blk, 0, stream, Wq, WqTh, WqTl);
    hipLaunchKernelGGL(trans_split, gT, blk, 0, stream, Wk, WkTh, WkTl);
    hipLaunchKernelGGL(trans_split, gT, blk, 0, stream, Wv, WvTh, WvTl);
    hipLaunchKernelGGL(trans_split, gT, blk, 0, stream, Wo, WoTh, WoTl);

    dim3 gProj(DIM / 128, MB / 128);   // (8, 32)
    dim3 gS(2048 / 128, MB / 128);     // (16, 32)
    dim3 gSm(1024);

    for (int b = 0; b < NBATCH; ++b) {
        const size_t xoff = (size_t)b * MB * DIM;
        hipLaunchKernelGGL(split_x, dim3(2048), blk, 0, stream, x + xoff, xh, xl);

        hipLaunchKernelGGL((btgemm<3,1>), gProj, blk, 0, stream,
            xh, xl, WqTh, WqTl, DIM, DIM, DIM,
            (float*)nullptr, Qh, Ql, nullptr, nullptr, nullptr, DIM, 1.0f);
        hipLaunchKernelGGL((btgemm<3,1>), gProj, blk, 0, stream,
            xh, xl, WkTh, WkTl, DIM, DIM, DIM,
            (float*)nullptr, Kh, Kl, nullptr, nullptr, nullptr, DIM, 1.0f);
        hipLaunchKernelGGL((btgemm<1,2>), gProj, blk, 0, stream,
            xh, nullptr, WvTh, nullptr, DIM, DIM, DIM,
            (float*)nullptr, Vt, nullptr, nullptr, nullptr, nullptr, MB, 1.0f);

        for (int h = 0; h < 2; ++h) {
            hipLaunchKernelGGL((btgemm<3,0>), gS, blk, 0, stream,
                Qh, Ql, Kh + (size_t)h * 2048 * DIM, Kl + (size_t)h * 2048 * DIM,
                DIM, DIM, DIM,
                S, nullptr, nullptr, nullptr, nullptr, nullptr, 2048, 8.0f);
            if (h == 0)
                hipLaunchKernelGGL((softmax_half<0>), gSm, blk, 0, stream, S, mrow, lrow, corr, invl);
            else
                hipLaunchKernelGGL((softmax_half<1>), gSm, blk, 0, stream, S, mrow, lrow, corr, invl);
            if (h == 0)
                hipLaunchKernelGGL((btgemm<1,0>), gProj, blk, 0, stream,
                    (ushort_t*)S, nullptr, Vt, nullptr, 4096, 4096, 2048,
                    Oac, nullptr, nullptr, nullptr, nullptr, nullptr, DIM, 1.0f);
            else
                hipLaunchKernelGGL((btgemm<1,4>), gProj, blk, 0, stream,
                    (ushort_t*)S, nullptr, Vt + 2048, nullptr, 4096, 4096, 2048,
                    (float*)nullptr, AO, nullptr, corr, invl, Oac, DIM, 1.0f);
        }

        hipLaunchKernelGGL((btgemm<1,0>), gProj, blk, 0, stream,
            AO, nullptr, WoTh, nullptr, DIM, DIM, DIM,
            out + xoff, nullptr, nullptr, nullptr, nullptr, nullptr, DIM, 1.0f);
    }
}

// Round 7
// 549.828 us; speedup vs baseline: 19.2232x; 1.2836x over previous
//
#include <hip/hip_runtime.h>

// MultiHeadSelfAttention (faithful: single logical head over full D=1024).
// B=2, S=4096, D=1024, SCALE = 8.0.
//
// Round 7 = round 6 resubmitted verbatim (round 6 died to an infra flake:
// container unresponsive before the bench ran).
//  - M-trick: Mt = Wk·Wq^T (once); y = x·Mt^T; S = y·x^T  (K never built,
//    one 3-pass projection per batch eliminated; x already hi/lo split)
//  - btgemm: BK=64 (2x kk sub-buffers, round-5 addressing verbatim),
//    XCD-bijective block swizzle, EPI3 bf16-out / EPI4 bf16 in-place merge
//  - Oacc bf16 in-place (aliases dead Wq/Wk split region)
// ws map (MiB): 0 xh | 16 xl | 32 yh | 48 yl | 64 Vt(8) | 72 S(32) |
//   104 stats | 112 Wqh/Wql/Wkh/Wkl -> Oacc(8) | 120 Mth | 122 Mtl |
//   124 WvTh | 126 WoTh   (= 128 total)

#define DIM    1024
#define SEQ    4096
#define NBATCH 2

typedef unsigned short ushort_t;
typedef __attribute__((ext_vector_type(8))) short bf16x8;
typedef __attribute__((ext_vector_type(4))) float f32x4;

__device__ __forceinline__ float bf2f(ushort_t u) {
    union { unsigned int i; float f; } v; v.i = ((unsigned int)u) << 16; return v.f;
}
__device__ __forceinline__ ushort_t f2bf(float f) {   // RNE
    union { float f; unsigned int i; } v; v.f = f;
    unsigned int x = v.i + (0x7fffu + ((v.i >> 16) & 1u));
    return (ushort_t)(x >> 16);
}
__device__ __forceinline__ void load_lds16(const void* g, void* l) {
    __builtin_amdgcn_global_load_lds(
        (const __attribute__((address_space(1))) unsigned int*)g,
        (__attribute__((address_space(3))) unsigned int*)l, 16, 0, 0);
}

// ---------------- f32 -> hi/lo bf16 split (2048 elems / block) ------------
__global__ __launch_bounds__(256) void split_pair(const float* __restrict__ src,
                                                  ushort_t* __restrict__ h,
                                                  ushort_t* __restrict__ l)
{
    int i = (blockIdx.x * 256 + threadIdx.x) * 8;
    float4 f0 = *(const float4*)(src + i);
    float4 f1 = *(const float4*)(src + i + 4);
    float v[8] = {f0.x, f0.y, f0.z, f0.w, f1.x, f1.y, f1.z, f1.w};
    ushort_t hh[8], ll[8];
    #pragma unroll
    for (int k = 0; k < 8; ++k) {
        hh[k] = f2bf(v[k]);
        ll[k] = f2bf(v[k] - bf2f(hh[k]));
    }
    unsigned int ph[4], pl[4];
    #pragma unroll
    for (int k = 0; k < 4; ++k) {
        ph[k] = (unsigned int)hh[2*k] | ((unsigned int)hh[2*k+1] << 16);
        pl[k] = (unsigned int)ll[2*k] | ((unsigned int)ll[2*k+1] << 16);
    }
    *(uint4*)(h + i) = make_uint4(ph[0], ph[1], ph[2], ph[3]);
    *(uint4*)(l + i) = make_uint4(pl[0], pl[1], pl[2], pl[3]);
}

// ---------------- W [1024][1024] f32 -> transposed bf16 (hi only) ---------
__global__ __launch_bounds__(256) void trans_hi(const float* __restrict__ W,
                                                ushort_t* __restrict__ Th)
{
    __shared__ float tile[64][65];
    const int r0 = blockIdx.y * 64, c0 = blockIdx.x * 64;
    const int tr = threadIdx.x >> 4, tc = (threadIdx.x & 15) * 4;
    #pragma unroll
    for (int p = 0; p < 4; ++p) {
        int r = tr + p * 16;
        float4 f = *(const float4*)&W[(size_t)(r0 + r) * DIM + c0 + tc];
        tile[r][tc + 0] = f.x; tile[r][tc + 1] = f.y;
        tile[r][tc + 2] = f.z; tile[r][tc + 3] = f.w;
    }
    __syncthreads();
    #pragma unroll
    for (int p = 0; p < 4; ++p) {
        int i = tr + p * 16;
        ushort_t h[4];
        #pragma unroll
        for (int k = 0; k < 4; ++k) h[k] = f2bf(tile[tc + k][i]);
        *(ushort4*)&Th[(size_t)(c0 + i) * DIM + r0 + tc] =
            make_ushort4(h[0], h[1], h[2], h[3]);
    }
}

// ---------------- universal B^T MFMA GEMM, BK=64 --------------------------
// C[M,N] = scale * A[M,K]·B[N,K]^T. 128x128 tile, 4 waves (64x64 quadrant).
// LDS per operand tile per kk: [128 rows][4 slots of 16B], slot ^= (row>>1)&3.
// EPI: 0 f32 | 1 split hi/lo bf16 | 2 bf16 transposed | 3 bf16
//      4 bf16 in-place merge: o1 = f2bf((bf2f(o1)*corr[row] + v)*invl[row])
template<int PASSES, int EPI>
__global__ __launch_bounds__(256, 2) void btgemm(
    const ushort_t* __restrict__ Ah, const ushort_t* __restrict__ Al,
    const ushort_t* __restrict__ Bh, const ushort_t* __restrict__ Bl,
    int sA, int sB, int Kdim,
    float* __restrict__ fout, ushort_t* __restrict__ o1, ushort_t* __restrict__ o2,
    const float* __restrict__ corr, const float* __restrict__ invl,
    int sC, float scale)
{
    __shared__ __align__(16) char smem[(PASSES == 3) ? 65536 : 32768];
    const int t    = threadIdx.x;
    const int lane = t & 63;
    const int wv   = t >> 6;
    const int lr   = lane & 15;
    const int lg   = lane >> 4;

    // XCD-aware bijective swizzle (all grids used are multiples of 8 blocks)
    const int gx = gridDim.x;
    int nwg = gx * gridDim.y;
    int wg  = blockIdx.y * gx + blockIdx.x;
    if ((nwg & 7) == 0) wg = (wg & 7) * (nwg >> 3) + (wg >> 3);
    const int bn = (wg % gx) * 128;
    const int bm = (wg / gx) * 128;

    const int wr = (wv >> 1) * 64;
    const int wc = (wv & 1) * 64;

    f32x4 acc[4][4];
    #pragma unroll
    for (int i = 0; i < 4; ++i)
        #pragma unroll
        for (int j = 0; j < 4; ++j) acc[i][j] = {0.f, 0.f, 0.f, 0.f};

    const ushort_t* srcs[4] = {Ah, Bh, Al, Bl};
    constexpr int NI = (PASSES == 3) ? 16 : 8;

    for (int k0 = 0; k0 < Kdim; k0 += 64) {
        // stage: per (tile, kk): 8 chunks of 16 rows (64 lanes x 16B each)
        #pragma unroll
        for (int i = 0; i < NI; ++i) {
            const int tile = i >> 2;            // compile-time after unroll
            const int kk   = (i >> 1) & 1;
            const int ch   = (i & 1) * 4 + wv;
            int unit = ch * 64 + lane;
            int row  = unit >> 2;
            int ls   = (unit & 3) ^ ((row >> 1) & 3);
            const ushort_t* g = srcs[tile]
                + (size_t)(((tile & 1) ? bn : bm) + row) * ((tile & 1) ? sB : sA)
                + k0 + kk * 32 + ls * 8;
            load_lds16(g, smem + tile * 16384 + kk * 8192 + ch * 1024);
        }
        __syncthreads();
        #pragma unroll
        for (int kk = 0; kk < 2; ++kk) {
            char* base = smem + kk * 8192;
            bf16x8 ah[4], bh[4], al[4], bl[4];
            #pragma unroll
            for (int r = 0; r < 4; ++r) {
                int ra = wr + r * 16 + lr;
                int rb = wc + r * 16 + lr;
                int oa = ((ra << 2) + (lg ^ ((ra >> 1) & 3))) * 16;
                int ob = ((rb << 2) + (lg ^ ((rb >> 1) & 3))) * 16;
                ah[r] = *(const bf16x8*)(base + oa);
                bh[r] = *(const bf16x8*)(base + 16384 + ob);
                if constexpr (PASSES == 3) {
                    al[r] = *(const bf16x8*)(base + 32768 + oa);
                    bl[r] = *(const bf16x8*)(base + 49152 + ob);
                }
            }
            #pragma unroll
            for (int i2 = 0; i2 < 4; ++i2)
                #pragma unroll
                for (int j = 0; j < 4; ++j) {
                    acc[i2][j] = __builtin_amdgcn_mfma_f32_16x16x32_bf16(ah[i2], bh[j], acc[i2][j], 0, 0, 0);
                    if constexpr (PASSES == 3) {
                        acc[i2][j] = __builtin_amdgcn_mfma_f32_16x16x32_bf16(ah[i2], bl[j], acc[i2][j], 0, 0, 0);
                        acc[i2][j] = __builtin_amdgcn_mfma_f32_16x16x32_bf16(al[i2], bh[j], acc[i2][j], 0, 0, 0);
                    }
                }
        }
        __syncthreads();
    }

    #pragma unroll
    for (int i = 0; i < 4; ++i)
        #pragma unroll
        for (int j = 0; j < 4; ++j) {
            int col = bn + wc + j * 16 + lr;
            #pragma unroll
            for (int reg = 0; reg < 4; ++reg) {
                int row = bm + wr + i * 16 + lg * 4 + reg;
                float v = acc[i][j][reg] * scale;
                if constexpr (EPI == 0) {
                    fout[(size_t)row * sC + col] = v;
                } else if constexpr (EPI == 1) {
                    ushort_t h = f2bf(v);
                    o1[(size_t)row * sC + col] = h;
                    o2[(size_t)row * sC + col] = f2bf(v - bf2f(h));
                } else if constexpr (EPI == 2) {
                    o1[(size_t)col * sC + row] = f2bf(v);
                } else if constexpr (EPI == 3) {
                    o1[(size_t)row * sC + col] = f2bf(v);
                } else {  // EPI == 4
                    size_t idx = (size_t)row * sC + col;
                    float old = bf2f(o1[idx]);
                    o1[idx] = f2bf((old * corr[row] + v) * invl[row]);
                }
            }
        }
}

// ---------------- row softmax over a 2048-col half, in-place P ------------
template<int HALF>
__global__ __launch_bounds__(256) void softmax_half(float* __restrict__ S,
                                                    float* __restrict__ mrow,
                                                    float* __restrict__ lrow,
                                                    float* __restrict__ corr,
                                                    float* __restrict__ invl)
{
    const int row  = blockIdx.x * 4 + (threadIdx.x >> 6);
    const int lane = threadIdx.x & 63;
    float* sp = S + (size_t)row * 2048;

    float v[32];
    float m = -INFINITY;
    #pragma unroll
    for (int c = 0; c < 8; ++c) {
        float4 f = *(const float4*)(sp + (c * 64 + lane) * 4);
        v[c*4+0] = f.x; v[c*4+1] = f.y; v[c*4+2] = f.z; v[c*4+3] = f.w;
        m = fmaxf(m, fmaxf(fmaxf(f.x, f.y), fmaxf(f.z, f.w)));
    }
    #pragma unroll
    for (int off = 32; off; off >>= 1) m = fmaxf(m, __shfl_xor(m, off));

    float mN = m, c1 = 1.f;
    if constexpr (HALF == 1) {
        float m1 = mrow[row];
        mN = fmaxf(m, m1);
        c1 = __expf(m1 - mN);
    }
    float p[32], l = 0.f;
    #pragma unroll
    for (int k = 0; k < 32; ++k) { p[k] = __expf(v[k] - mN); l += p[k]; }
    #pragma unroll
    for (int off = 32; off; off >>= 1) l += __shfl_xor(l, off);

    if constexpr (HALF == 0) {
        if (lane == 0) { mrow[row] = mN; lrow[row] = l; }
    } else {
        if (lane == 0) {
            float L = lrow[row] * c1 + l;
            corr[row] = c1;
            invl[row] = 1.f / L;
        }
    }
    ushort_t* pp = (ushort_t*)sp;
    #pragma unroll
    for (int c = 0; c < 8; ++c) {
        ushort4 u = make_ushort4(f2bf(p[c*4+0]), f2bf(p[c*4+1]),
                                 f2bf(p[c*4+2]), f2bf(p[c*4+3]));
        *(ushort4*)(pp + (c * 64 + lane) * 4) = u;
    }
}

extern "C" void kernel_launch(void* const* d_in, const int* in_sizes, int n_in,
                              void* d_out, int out_size, void* d_ws, size_t ws_size,
                              hipStream_t stream) {
    const float* x  = (const float*)d_in[0];
    const float* Wq = (const float*)d_in[1];
    const float* Wk = (const float*)d_in[2];
    const float* Wv = (const float*)d_in[3];
    const float* Wo = (const float*)d_in[4];
    float* out = (float*)d_out;

    char* ws = (char*)d_ws;
    const size_t MiB = 1024 * 1024;
    ushort_t* xh   = (ushort_t*)(ws +   0 * MiB);   // [8192][1024]
    ushort_t* xl   = (ushort_t*)(ws +  16 * MiB);
    ushort_t* yh   = (ushort_t*)(ws +  32 * MiB);   // [8192][1024]
    ushort_t* yl   = (ushort_t*)(ws +  48 * MiB);
    ushort_t* Vt   = (ushort_t*)(ws +  64 * MiB);   // [1024][4096] per batch
    float*    S    = (float*)   (ws +  72 * MiB);   // [4096][2048] f32 / P bf16
    float*    mrow = (float*)   (ws + 104 * MiB);
    float*    lrow = mrow + 4096;
    float*    corr = mrow + 8192;
    float*    invl = mrow + 12288;
    ushort_t* Wqh  = (ushort_t*)(ws + 112 * MiB);   // dead after Mt
    ushort_t* Wql  = (ushort_t*)(ws + 114 * MiB);
    ushort_t* Wkh  = (ushort_t*)(ws + 116 * MiB);
    ushort_t* Wkl  = (ushort_t*)(ws + 118 * MiB);
    ushort_t* Oacc = (ushort_t*)(ws + 112 * MiB);   // [4096][1024] bf16, aliases W splits
    ushort_t* Mth  = (ushort_t*)(ws + 120 * MiB);
    ushort_t* Mtl  = (ushort_t*)(ws + 122 * MiB);
    ushort_t* WvTh = (ushort_t*)(ws + 124 * MiB);
    ushort_t* WoTh = (ushort_t*)(ws + 126 * MiB);

    dim3 blk(256);
    hipLaunchKernelGGL(split_pair, dim3(512), blk, 0, stream, Wq, Wqh, Wql);
    hipLaunchKernelGGL(split_pair, dim3(512), blk, 0, stream, Wk, Wkh, Wkl);
    hipLaunchKernelGGL(trans_hi, dim3(16, 16), blk, 0, stream, Wv, WvTh);
    hipLaunchKernelGGL(trans_hi, dim3(16, 16), blk, 0, stream, Wo, WoTh);
    // Mt = Wk · Wq^T   (3-pass, split epilogue)
    hipLaunchKernelGGL((btgemm<3,1>), dim3(8, 8), blk, 0, stream,
        Wkh, Wkl, Wqh, Wql, DIM, DIM, DIM,
        (float*)nullptr, Mth, Mtl, nullptr, nullptr, DIM, 1.0f);
    // x split (both batches)
    hipLaunchKernelGGL(split_pair, dim3(4096), blk, 0, stream, x, xh, xl);
    // y = x · Mt^T   (both batches; 3-pass, split epilogue)
    hipLaunchKernelGGL((btgemm<3,1>), dim3(8, 64), blk, 0, stream,
        xh, xl, Mth, Mtl, DIM, DIM, DIM,
        (float*)nullptr, yh, yl, nullptr, nullptr, DIM, 1.0f);

    for (int b = 0; b < NBATCH; ++b) {
        const size_t ro = (size_t)b * 4096;
        // Vt = (x_b · Wv)^T
        hipLaunchKernelGGL((btgemm<1,2>), dim3(8, 32), blk, 0, stream,
            xh + ro * DIM, nullptr, WvTh, nullptr, DIM, DIM, DIM,
            (float*)nullptr, Vt, nullptr, nullptr, nullptr, 4096, 1.0f);
        for (int h = 0; h < 2; ++h) {
            // S = 8 * y_b · x_{b,half}^T   (3-pass)
            hipLaunchKernelGGL((btgemm<3,0>), dim3(16, 32), blk, 0, stream,
                yh + ro * DIM, yl + ro * DIM,
                xh + (ro + (size_t)h * 2048) * DIM, xl + (ro + (size_t)h * 2048) * DIM,
                DIM, DIM, DIM,
                S, nullptr, nullptr, nullptr, nullptr, 2048, 8.0f);
            if (h == 0) {
                hipLaunchKernelGGL((softmax_half<0>), dim3(1024), blk, 0, stream, S, mrow, lrow, corr, invl);
                hipLaunchKernelGGL((btgemm<1,3>), dim3(8, 32), blk, 0, stream,
                    (ushort_t*)S, nullptr, Vt, nullptr, 4096, 4096, 2048,
                    (float*)nullptr, Oacc, nullptr, nullptr, nullptr, DIM, 1.0f);
            } else {
                hipLaunchKernelGGL((softmax_half<1>), dim3(1024), blk, 0, stream, S, mrow, lrow, corr, invl);
                hipLaunchKernelGGL((btgemm<1,4>), dim3(8, 32), blk, 0, stream,
                    (ushort_t*)S, nullptr, Vt + 2048, nullptr, 4096, 4096, 2048,
                    (float*)nullptr, Oacc, nullptr, corr, invl, DIM, 1.0f);
            }
        }
        // out_b = AO · Wo   (AO = Oacc bf16)
        hipLaunchKernelGGL((btgemm<1,0>), dim3(8, 32), blk, 0, stream,
            Oacc, nullptr, WoTh, nullptr, DIM, DIM, DIM,
            out + ro * DIM, nullptr, nullptr, nullptr, nullptr, DIM, 1.0f);
    }
}